// Round 1
// baseline (40.174 us; speedup 1.0000x reference)
//
#include <hip/hip_runtime.h>

// One 64-lane wave per word. Lane l owns output bins [4l, 4l+4).
// Block = 256 threads = 4 waves = 4 words per block.
__global__ __launch_bounds__(256) void char_hist_kernel(const int* __restrict__ tok,
                                                        float* __restrict__ out,
                                                        int num_words) {
    const int wave = threadIdx.x >> 6;
    const int lane = threadIdx.x & 63;
    const int word = blockIdx.x * 4 + wave;
    if (word >= num_words) return;

    // Load the word's 16 tokens (64 B). All lanes issue the same addresses;
    // the coalescer collapses these to single transactions (L1 broadcast).
    const int4* tp = reinterpret_cast<const int4*>(tok + (size_t)word * 16);
    const int4 a = tp[0];
    const int4 b = tp[1];
    const int4 c = tp[2];
    const int4 d = tp[3];
    const int t[16] = {a.x, a.y, a.z, a.w,
                       b.x, b.y, b.z, b.w,
                       c.x, c.y, c.z, c.w,
                       d.x, d.y, d.z, d.w};

    const int b0 = lane * 4;
    int c0 = 0, c1 = 0, c2 = 0, c3 = 0;
#pragma unroll
    for (int i = 0; i < 16; ++i) {
        c0 += (t[i] == b0);
        c1 += (t[i] == b0 + 1);
        c2 += (t[i] == b0 + 2);
        c3 += (t[i] == b0 + 3);
    }
    // Padding exclusion: bin 0 only ever receives tokens equal to PADDING_IDX=0.
    if (lane == 0) c0 = 0;

    const float4 r = make_float4((float)c0, (float)c1, (float)c2, (float)c3);
    reinterpret_cast<float4*>(out)[(size_t)word * 64 + lane] = r;
}

extern "C" void kernel_launch(void* const* d_in, const int* in_sizes, int n_in,
                              void* d_out, int out_size, void* d_ws, size_t ws_size,
                              hipStream_t stream) {
    const int* tok = (const int*)d_in[0];
    float* out = (float*)d_out;
    const int num_words = in_sizes[0] / 16;  // 128*1024 = 131072
    const int blocks = (num_words + 3) / 4;  // 4 words per 256-thread block
    char_hist_kernel<<<blocks, 256, 0, stream>>>(tok, out, num_words);
}

// Round 2
// 29.439 us; speedup vs baseline: 1.3646x; 1.3646x over previous
//
#include <hip/hip_runtime.h>

// Per-wave LDS histogram. Each 64-lane wave owns WPW=4 words:
//   - zero its 4 KiB LDS region (4 x ds_write_b128 per lane)
//   - lane l atomically bumps hist[l>>4][token(l&15)] via ds_add_f32
//   - read back float4 per word and store coalesced (1 KiB per word per wave)
// Padding (id 0): only pad tokens can land in bin 0, so bin 0 is forced to 0
// at readout.
#define WPW 4

__global__ __launch_bounds__(256) void char_hist_kernel(const int* __restrict__ tok,
                                                        float* __restrict__ out,
                                                        int num_words) {
    __shared__ float hist[4][WPW * 256];  // 16 KiB per 256-thread block
    const int wave = threadIdx.x >> 6;
    const int lane = threadIdx.x & 63;
    float* h = hist[wave];
    float4* h4 = reinterpret_cast<float4*>(h);

    const long word_base = ((long)blockIdx.x * 4 + wave) * WPW;

    // Zero this wave's histogram region: 4 x 1 KiB, one float4 per lane each.
#pragma unroll
    for (int r = 0; r < WPW; ++r)
        h4[r * 64 + lane] = make_float4(0.f, 0.f, 0.f, 0.f);

    __syncthreads();  // cheap; guarantees zeroing is visible before atomics

    // Scatter: lane l handles token (l & 15) of word (l >> 4).
    const long ti = word_base * 16 + lane;  // == (word_base + (lane>>4))*16 + (lane&15)
    if (ti < (long)num_words * 16) {
        const int t = tok[ti];
        atomicAdd(&h[(lane >> 4) * 256 + t], 1.0f);  // ds_add_f32
    }

    __syncthreads();  // atomics visible before readback

    // Readback + store: per word, lane l owns bins [4l, 4l+4).
#pragma unroll
    for (int r = 0; r < WPW; ++r) {
        const long word = word_base + r;
        if (word < num_words) {
            float4 v = h4[r * 64 + lane];
            if (lane == 0) v.x = 0.f;  // exclude padding_idx bin
            reinterpret_cast<float4*>(out)[word * 64 + lane] = v;
        }
    }
}

extern "C" void kernel_launch(void* const* d_in, const int* in_sizes, int n_in,
                              void* d_out, int out_size, void* d_ws, size_t ws_size,
                              hipStream_t stream) {
    const int* tok = (const int*)d_in[0];
    float* out = (float*)d_out;
    const int num_words = in_sizes[0] / 16;               // 131072
    const int words_per_block = 4 * WPW;                  // 4 waves x 4 words
    const int blocks = (num_words + words_per_block - 1) / words_per_block;
    char_hist_kernel<<<blocks, 256, 0, stream>>>(tok, out, num_words);
}